// Round 14
// baseline (83.846 us; speedup 1.0000x reference)
//
#include <hip/hip_runtime.h>

#define BATCH 4
#define NPTS 8192
#define TPB 256
#define RSPLIT 4                    // row-split partial-min slices (no atomics)
#define TOTAL (2 * BATCH * NPTS)    // 65536 output slots
#define GRID (8 * 32 * RSPLIT)      // sides x colgroups x rowsplit = 1024 blocks
#define NCHUNK 8                    // 8 chunks x 256 rows = 2048 rows per block

typedef short bf16x8 __attribute__((ext_vector_type(8)));
typedef float f32x16 __attribute__((ext_vector_type(16)));

__device__ __forceinline__ unsigned short b16(float f) {   // fp32 -> bf16 RNE
  unsigned u = __float_as_uint(f);
  return (unsigned short)((u + 0x7FFFu + ((u >> 16) & 1u)) >> 16);
}
__device__ __forceinline__ float b2f(unsigned short h) {
  return __uint_as_float(((unsigned)h) << 16);
}

// K=16 packed rows (R8..R12-verified exact, absmax 0.0):
//  roleA(x): [(-2x)h(3), (-2x)l(3), (-2x)h(3), x2h, x2l, 1,   1,  0,0,0]
//  roleB(y): [yh(3),     yh(3),     yl(3),     1,   1, y2h, y2l, 0,0,0]
// roleA.roleB = squared distance minus (-2x)l.yl (~1e-5 << 9.3e-4 threshold).
__device__ __forceinline__ void pack_halves(uint4* lo, uint4* hi, float cx,
                                            float cy, float cz, bool roleA) {
  float n2 = cx * cx + cy * cy + cz * cz;
  float vx = roleA ? -2.f * cx : cx;
  float vy = roleA ? -2.f * cy : cy;
  float vz = roleA ? -2.f * cz : cz;
  unsigned hx = b16(vx), hy = b16(vy), hz = b16(vz);
  unsigned lx = b16(vx - b2f(hx)), ly = b16(vy - b2f(hy)), lz = b16(vz - b2f(hz));
  unsigned nh = b16(n2), nl = b16(n2 - b2f(nh));
  const unsigned ONE = 0x3F80u;
  if (roleA) {
    *lo = make_uint4(hx | (hy << 16), hz | (lx << 16), ly | (lz << 16), hx | (hy << 16));
    *hi = make_uint4(hz | (nh << 16), nl | (ONE << 16), ONE, 0u);
  } else {
    *lo = make_uint4(hx | (hy << 16), hz | (hx << 16), hy | (hz << 16), lx | (ly << 16));
    *hi = make_uint4(lz | (ONE << 16), ONE | (nh << 16), nl, 0u);
  }
}

// R12 tiling + double-buffered sB (ONE barrier per 256-row chunk; pack of
// chunk c+1 overlaps MFMA+min3 of chunk c) + R13's 4-chain min-tree ILP.
// Block = (side, colgroup of 256 A-cols, row-quarter of 2048 B-rows).
// LDS frag layout LANE-ORDERED (writes and reads lane-stride-1, 2-way max).
// Row-axis min is in-lane (C/D: col=lane&31, row=(reg&3)+8*(reg>>2)+4*g).
__global__ __launch_bounds__(TPB) void chamfer_nn(
    const float* __restrict__ pred, const float* __restrict__ gt,
    float* __restrict__ partial, float* __restrict__ out) {
  __shared__ __align__(16) unsigned short sA[256 * 16];      // 8 KB col frags
  __shared__ __align__(16) unsigned short sB[2][256 * 16];   // 2 x 8 KB row frags

  int blk = blockIdx.x;
  int rq   = blk & (RSPLIT - 1);      // row quarter
  int cg   = (blk >> 2) & 31;         // colgroup (256 cols)
  int side = blk >> 7;                // dir*4 + b
  int dir = side >> 2, b = side & 3;

  const float* As = (dir ? gt : pred) + (size_t)b * NPTS * 3;  // cols (outputs)
  const float* Bs = (dir ? pred : gt) + (size_t)b * NPTS * 3;  // rows (min'ed)

  int t = threadIdx.x;
  if (blk == 0 && t == 0) out[0] = 0.f;   // zero accumulator for reduce pass

  int rowbase = rq * (NPTS / RSPLIT);
  unsigned short* u0A = sA + ((t >> 5) * 64 + (t & 31)) * 8;

  // Prologue: pack 256 A-cols (1/thread) + first row chunk into buffer 0.
  {
    int gp = cg * 256 + t;
    uint4 lo, hi;
    pack_halves(&lo, &hi, As[gp * 3], As[gp * 3 + 1], As[gp * 3 + 2], false);
    *(uint4*)u0A = lo;
    *(uint4*)(u0A + 32 * 8) = hi;
    int gq = rowbase + t;
    pack_halves(&lo, &hi, Bs[gq * 3], Bs[gq * 3 + 1], Bs[gq * 3 + 2], true);
    unsigned short* u0B = sB[0] + ((t >> 5) * 64 + (t & 31)) * 8;
    *(uint4*)u0B = lo;
    *(uint4*)(u0B + 32 * 8) = hi;
  }
  __syncthreads();

  int w = t >> 6, lane = t & 63;
  // Resident col-operands: wave w owns col-tiles 2w, 2w+1.
  bf16x8 af0 = *(const bf16x8*)(sA + ((2 * w) * 64 + lane) * 8);
  bf16x8 af1 = *(const bf16x8*)(sA + ((2 * w + 1) * 64 + lane) * 8);

  const f32x16 Z = {0.f,0.f,0.f,0.f,0.f,0.f,0.f,0.f,0.f,0.f,0.f,0.f,0.f,0.f,0.f,0.f};
  float m0a = 3.4e38f, m0b = 3.4e38f, m1a = 3.4e38f, m1b = 3.4e38f;

  #pragma unroll 1
  for (int c = 0; c < NCHUNK; ++c) {
    // Pack chunk c+1 into the other buffer (overlaps compute below; its
    // target buffer's reads finished before the previous barrier).
    if (c + 1 < NCHUNK) {
      int gp = rowbase + (c + 1) * 256 + t;
      uint4 lo, hi;
      pack_halves(&lo, &hi, Bs[gp * 3], Bs[gp * 3 + 1], Bs[gp * 3 + 2], true);
      unsigned short* u0 = sB[(c + 1) & 1] + ((t >> 5) * 64 + (t & 31)) * 8;
      *(uint4*)u0 = lo;
      *(uint4*)(u0 + 32 * 8) = hi;
    }
    // Compute chunk c: 8 rowtiles x (1 ds_read_b128 + 2 MFMA + 16 min3),
    // 4 independent 4-deep min3 chains to ride out MFMA latency.
    const unsigned short* buf = sB[c & 1];
    #pragma unroll 4
    for (int rt = 0; rt < 8; ++rt) {
      bf16x8 bf = *(const bf16x8*)(buf + (rt * 64 + lane) * 8);
      f32x16 d0 = __builtin_amdgcn_mfma_f32_32x32x16_bf16(bf, af0, Z, 0, 0, 0);
      f32x16 d1 = __builtin_amdgcn_mfma_f32_32x32x16_bf16(bf, af1, Z, 0, 0, 0);
      #pragma unroll
      for (int r = 0; r < 16; r += 4) {
        m0a = fminf(fminf(m0a, d0[r]), d0[r + 1]);       // v_min3_f32
        m0b = fminf(fminf(m0b, d0[r + 2]), d0[r + 3]);
        m1a = fminf(fminf(m1a, d1[r]), d1[r + 1]);
        m1b = fminf(fminf(m1b, d1[r + 2]), d1[r + 3]);
      }
    }
    __syncthreads();   // one barrier/chunk: covers dbuf swap both ways
  }

  float m0 = fminf(m0a, m0b), m1 = fminf(m1a, m1b);
  m0 = fminf(m0, __shfl_xor(m0, 32, 64));   // merge complementary row halves
  m1 = fminf(m1, __shfl_xor(m1, 32, 64));
  if (lane < 32) {
    float* dst = partial + (size_t)rq * TOTAL + (size_t)side * NPTS + cg * 256;
    dst[w * 64 + lane]      = fmaxf(m0, 0.f);
    dst[w * 64 + 32 + lane] = fmaxf(m1, 0.f);
  }
}

// Reduce: min over RSPLIT partials per slot, block-sum, one atomicAdd/block.
// out[0] was zeroed by chamfer_nn (stream-ordered before this kernel).
__global__ __launch_bounds__(TPB) void chamfer_reduce(
    const float* __restrict__ partial, float* __restrict__ out) {
  int t = threadIdx.x;
  int s = blockIdx.x * TPB + t;       // slot 0..65535
  float v = partial[s];
  #pragma unroll
  for (int r = 1; r < RSPLIT; ++r)
    v = fminf(v, partial[(size_t)r * TOTAL + s]);
  #pragma unroll
  for (int off = 32; off > 0; off >>= 1) v += __shfl_down(v, off, 64);
  __shared__ float wsum[4];
  int wave = t >> 6, lane = t & 63;
  if (lane == 0) wsum[wave] = v;
  __syncthreads();
  if (t == 0) {
    float tot = (wsum[0] + wsum[1]) + (wsum[2] + wsum[3]);
    atomicAdd(out, tot * (1.f / (float)(BATCH * NPTS)));
  }
}

extern "C" void kernel_launch(void* const* d_in, const int* in_sizes, int n_in,
                              void* d_out, int out_size, void* d_ws, size_t ws_size,
                              hipStream_t stream) {
  const float* pred = (const float*)d_in[0];
  const float* gt   = (const float*)d_in[1];
  float* out        = (float*)d_out;
  float* partial    = (float*)d_ws;   // RSPLIT x 65536 floats = 1 MB

  chamfer_nn<<<dim3(GRID), dim3(TPB), 0, stream>>>(pred, gt, partial, out);
  chamfer_reduce<<<dim3(TOTAL / TPB), dim3(TPB), 0, stream>>>(partial, out);
}

// Round 15
// 82.568 us; speedup vs baseline: 1.0155x; 1.0155x over previous
//
#include <hip/hip_runtime.h>

#define BATCH 4
#define NPTS 8192
#define TPB 256
#define RSPLIT 4                    // row-split partial-min slices (no atomics)
#define TOTAL (2 * BATCH * NPTS)    // 65536 output slots
#define GRID (8 * 32 * RSPLIT)      // sides x colgroups x rowsplit = 1024 blocks
#define NCHUNK 4                    // 4 chunks x 512 rows = 2048 rows per block

typedef short bf16x8 __attribute__((ext_vector_type(8)));
typedef float f32x16 __attribute__((ext_vector_type(16)));

__device__ __forceinline__ unsigned short b16(float f) {   // fp32 -> bf16 RNE
  unsigned u = __float_as_uint(f);
  return (unsigned short)((u + 0x7FFFu + ((u >> 16) & 1u)) >> 16);
}
__device__ __forceinline__ float b2f(unsigned short h) {
  return __uint_as_float(((unsigned)h) << 16);
}

// K=16 packed rows (R8..R12-verified exact, absmax 0.0):
//  roleA(x): [(-2x)h(3), (-2x)l(3), (-2x)h(3), x2h, x2l, 1,   1,  0,0,0]
//  roleB(y): [yh(3),     yh(3),     yl(3),     1,   1, y2h, y2l, 0,0,0]
// roleA.roleB = squared distance minus (-2x)l.yl (~1e-5 << 9.3e-4 threshold).
__device__ __forceinline__ void pack_halves(uint4* lo, uint4* hi, float cx,
                                            float cy, float cz, bool roleA) {
  float n2 = cx * cx + cy * cy + cz * cz;
  float vx = roleA ? -2.f * cx : cx;
  float vy = roleA ? -2.f * cy : cy;
  float vz = roleA ? -2.f * cz : cz;
  unsigned hx = b16(vx), hy = b16(vy), hz = b16(vz);
  unsigned lx = b16(vx - b2f(hx)), ly = b16(vy - b2f(hy)), lz = b16(vz - b2f(hz));
  unsigned nh = b16(n2), nl = b16(n2 - b2f(nh));
  const unsigned ONE = 0x3F80u;
  if (roleA) {
    *lo = make_uint4(hx | (hy << 16), hz | (lx << 16), ly | (lz << 16), hx | (hy << 16));
    *hi = make_uint4(hz | (nh << 16), nl | (ONE << 16), ONE, 0u);
  } else {
    *lo = make_uint4(hx | (hy << 16), hz | (hx << 16), hy | (hz << 16), lx | (ly << 16));
    *hi = make_uint4(lz | (ONE << 16), ONE | (nh << 16), nl, 0u);
  }
}

// R12 structure EXACTLY (RSPLIT=4, 512-row chunks, 2 barriers/chunk,
// lane-ordered LDS) + in-loop software pipeline: rowtile rt+1's
// ds_read + 2 MFMAs issue BEFORE rt's 16 min3, hiding MFMA latency
// under VALU issue. One extra d-pair in flight (+32 VGPR).
// Row-axis min is in-lane (C/D: col=lane&31, row=(reg&3)+8*(reg>>2)+4*g).
__global__ __launch_bounds__(TPB) void chamfer_nn(
    const float* __restrict__ pred, const float* __restrict__ gt,
    float* __restrict__ partial, float* __restrict__ out) {
  __shared__ __align__(16) unsigned short sA[256 * 16];   // 8 KB col frags
  __shared__ __align__(16) unsigned short sB[512 * 16];   // 16 KB row-chunk frags

  int blk = blockIdx.x;
  int rq   = blk & (RSPLIT - 1);      // row quarter
  int cg   = (blk >> 2) & 31;         // colgroup (256 cols)
  int side = blk >> 7;                // dir*4 + b
  int dir = side >> 2, b = side & 3;

  const float* As = (dir ? gt : pred) + (size_t)b * NPTS * 3;  // cols (outputs)
  const float* Bs = (dir ? pred : gt) + (size_t)b * NPTS * 3;  // rows (min'ed)

  int t = threadIdx.x;
  if (blk == 0 && t == 0) out[0] = 0.f;   // zero accumulator for reduce pass

  // Pack this block's 256 A-cols (1/thread) into lane-ordered sA.
  {
    int gp = cg * 256 + t;
    uint4 lo, hi;
    pack_halves(&lo, &hi, As[gp * 3], As[gp * 3 + 1], As[gp * 3 + 2], false);
    unsigned short* u0 = sA + ((t >> 5) * 64 + (t & 31)) * 8;
    *(uint4*)u0 = lo;
    *(uint4*)(u0 + 32 * 8) = hi;
  }
  __syncthreads();

  int w = t >> 6, lane = t & 63;
  // Resident col-operands: wave w owns col-tiles 2w, 2w+1.
  bf16x8 af0 = *(const bf16x8*)(sA + ((2 * w) * 64 + lane) * 8);
  bf16x8 af1 = *(const bf16x8*)(sA + ((2 * w + 1) * 64 + lane) * 8);

  const f32x16 Z = {0.f,0.f,0.f,0.f,0.f,0.f,0.f,0.f,0.f,0.f,0.f,0.f,0.f,0.f,0.f,0.f};
  float m0a = 3.4e38f, m0b = 3.4e38f, m1a = 3.4e38f, m1b = 3.4e38f;
  int rowbase = rq * (NPTS / RSPLIT);

  #pragma unroll 1
  for (int c = 0; c < NCHUNK; ++c) {  // chunks of 512 rows
    // Pack 2 rows/thread ({t, 256+t}: keeps ds_write lane-stride 1).
    #pragma unroll
    for (int h = 0; h < 2; ++h) {
      int p = h * 256 + t;            // local row in chunk
      int gp = rowbase + c * 512 + p;
      uint4 lo, hi;
      pack_halves(&lo, &hi, Bs[gp * 3], Bs[gp * 3 + 1], Bs[gp * 3 + 2], true);
      unsigned short* u0 = sB + ((p >> 5) * 64 + (p & 31)) * 8;
      *(uint4*)u0 = lo;
      *(uint4*)(u0 + 32 * 8) = hi;
    }
    __syncthreads();

    // Pipelined 16 rowtiles: MFMAs of rt+1 in flight while reducing rt.
    bf16x8 bf0 = *(const bf16x8*)(sB + (0 * 64 + lane) * 8);
    f32x16 d0 = __builtin_amdgcn_mfma_f32_32x32x16_bf16(bf0, af0, Z, 0, 0, 0);
    f32x16 d1 = __builtin_amdgcn_mfma_f32_32x32x16_bf16(bf0, af1, Z, 0, 0, 0);
    #pragma unroll
    for (int rt = 0; rt < 16; ++rt) {
      f32x16 e0, e1;
      if (rt + 1 < 16) {
        bf16x8 nb = *(const bf16x8*)(sB + ((rt + 1) * 64 + lane) * 8);
        e0 = __builtin_amdgcn_mfma_f32_32x32x16_bf16(nb, af0, Z, 0, 0, 0);
        e1 = __builtin_amdgcn_mfma_f32_32x32x16_bf16(nb, af1, Z, 0, 0, 0);
      }
      #pragma unroll
      for (int r = 0; r < 16; r += 4) {   // 4 independent 4-deep min3 chains
        m0a = fminf(fminf(m0a, d0[r]), d0[r + 1]);       // v_min3_f32
        m0b = fminf(fminf(m0b, d0[r + 2]), d0[r + 3]);
        m1a = fminf(fminf(m1a, d1[r]), d1[r + 1]);
        m1b = fminf(fminf(m1b, d1[r + 2]), d1[r + 3]);
      }
      if (rt + 1 < 16) { d0 = e0; d1 = e1; }
    }
    __syncthreads();                  // sB reads done before next pack
  }

  float m0 = fminf(m0a, m0b), m1 = fminf(m1a, m1b);
  m0 = fminf(m0, __shfl_xor(m0, 32, 64));   // merge complementary row halves
  m1 = fminf(m1, __shfl_xor(m1, 32, 64));
  if (lane < 32) {
    float* dst = partial + (size_t)rq * TOTAL + (size_t)side * NPTS + cg * 256;
    dst[w * 64 + lane]      = fmaxf(m0, 0.f);
    dst[w * 64 + 32 + lane] = fmaxf(m1, 0.f);
  }
}

// Reduce: min over RSPLIT partials per slot, block-sum, one atomicAdd/block.
// out[0] was zeroed by chamfer_nn (stream-ordered before this kernel).
__global__ __launch_bounds__(TPB) void chamfer_reduce(
    const float* __restrict__ partial, float* __restrict__ out) {
  int t = threadIdx.x;
  int s = blockIdx.x * TPB + t;       // slot 0..65535
  float v = partial[s];
  #pragma unroll
  for (int r = 1; r < RSPLIT; ++r)
    v = fminf(v, partial[(size_t)r * TOTAL + s]);
  #pragma unroll
  for (int off = 32; off > 0; off >>= 1) v += __shfl_down(v, off, 64);
  __shared__ float wsum[4];
  int wave = t >> 6, lane = t & 63;
  if (lane == 0) wsum[wave] = v;
  __syncthreads();
  if (t == 0) {
    float tot = (wsum[0] + wsum[1]) + (wsum[2] + wsum[3]);
    atomicAdd(out, tot * (1.f / (float)(BATCH * NPTS)));
  }
}

extern "C" void kernel_launch(void* const* d_in, const int* in_sizes, int n_in,
                              void* d_out, int out_size, void* d_ws, size_t ws_size,
                              hipStream_t stream) {
  const float* pred = (const float*)d_in[0];
  const float* gt   = (const float*)d_in[1];
  float* out        = (float*)d_out;
  float* partial    = (float*)d_ws;   // RSPLIT x 65536 floats = 1 MB

  chamfer_nn<<<dim3(GRID), dim3(TPB), 0, stream>>>(pred, gt, partial, out);
  chamfer_reduce<<<dim3(TOTAL / TPB), dim3(TPB), 0, stream>>>(partial, out);
}

// Round 16
// 76.150 us; speedup vs baseline: 1.1011x; 1.0843x over previous
//
#include <hip/hip_runtime.h>

#define BATCH 4
#define NPTS 8192
#define TPB 256
#define RSPLIT 4                    // row-split partial-min slices (no atomics)
#define TOTAL (2 * BATCH * NPTS)    // 65536 output slots
#define GRID (8 * 32 * RSPLIT)      // sides x colgroups x rowsplit = 1024 blocks

typedef short bf16x8 __attribute__((ext_vector_type(8)));
typedef float f32x16 __attribute__((ext_vector_type(16)));

__device__ __forceinline__ unsigned short b16(float f) {   // fp32 -> bf16 RNE
  unsigned u = __float_as_uint(f);
  return (unsigned short)((u + 0x7FFFu + ((u >> 16) & 1u)) >> 16);
}
__device__ __forceinline__ float b2f(unsigned short h) {
  return __uint_as_float(((unsigned)h) << 16);
}

// K=16 packed rows (R8..R12-verified exact, absmax 0.0):
//  roleA(x): [(-2x)h(3), (-2x)l(3), (-2x)h(3), x2h, x2l, 1,   1,  0,0,0]
//  roleB(y): [yh(3),     yh(3),     yl(3),     1,   1, y2h, y2l, 0,0,0]
// roleA.roleB = squared distance minus (-2x)l.yl (~1e-5 << 9.3e-4 threshold).
__device__ __forceinline__ void pack_halves(uint4* lo, uint4* hi, float cx,
                                            float cy, float cz, bool roleA) {
  float n2 = cx * cx + cy * cy + cz * cz;
  float vx = roleA ? -2.f * cx : cx;
  float vy = roleA ? -2.f * cy : cy;
  float vz = roleA ? -2.f * cz : cz;
  unsigned hx = b16(vx), hy = b16(vy), hz = b16(vz);
  unsigned lx = b16(vx - b2f(hx)), ly = b16(vy - b2f(hy)), lz = b16(vz - b2f(hz));
  unsigned nh = b16(n2), nl = b16(n2 - b2f(nh));
  const unsigned ONE = 0x3F80u;
  if (roleA) {
    *lo = make_uint4(hx | (hy << 16), hz | (lx << 16), ly | (lz << 16), hx | (hy << 16));
    *hi = make_uint4(hz | (nh << 16), nl | (ONE << 16), ONE, 0u);
  } else {
    *lo = make_uint4(hx | (hy << 16), hz | (hx << 16), hy | (hz << 16), lx | (ly << 16));
    *hi = make_uint4(lz | (ONE << 16), ONE | (nh << 16), nl, 0u);
  }
}

// R12 champion structure, verbatim (75.9 us): self-contained, no atomics,
// conflict-free lane-ordered LDS, RSPLIT=4, 512-row chunks, 2 barriers/chunk.
// Row-axis min is in-lane (C/D: col=lane&31, row=(reg&3)+8*(reg>>2)+4*g).
// R13 (RSPLIT=8), R14 (dbuf), R15 (sw-pipeline) all regressed vs this.
__global__ __launch_bounds__(TPB, 4) void chamfer_nn(
    const float* __restrict__ pred, const float* __restrict__ gt,
    float* __restrict__ partial, float* __restrict__ out) {
  __shared__ __align__(16) unsigned short sA[256 * 16];   // 8 KB col frags
  __shared__ __align__(16) unsigned short sB[512 * 16];   // 16 KB row-chunk frags

  int blk = blockIdx.x;
  int rq   = blk & (RSPLIT - 1);      // row quarter
  int cg   = (blk >> 2) & 31;         // colgroup (256 cols)
  int side = blk >> 7;                // dir*4 + b
  int dir = side >> 2, b = side & 3;

  const float* As = (dir ? gt : pred) + (size_t)b * NPTS * 3;  // cols (outputs)
  const float* Bs = (dir ? pred : gt) + (size_t)b * NPTS * 3;  // rows (min'ed)

  int t = threadIdx.x;
  if (blk == 0 && t == 0) out[0] = 0.f;   // zero accumulator for reduce pass

  // Pack this block's 256 A-cols (1/thread) into lane-ordered sA.
  {
    int gp = cg * 256 + t;
    uint4 lo, hi;
    pack_halves(&lo, &hi, As[gp * 3], As[gp * 3 + 1], As[gp * 3 + 2], false);
    unsigned short* u0 = sA + ((t >> 5) * 64 + (t & 31)) * 8;
    *(uint4*)u0 = lo;
    *(uint4*)(u0 + 32 * 8) = hi;
  }
  __syncthreads();

  int w = t >> 6, lane = t & 63;
  // Resident col-operands: wave w owns col-tiles 2w, 2w+1.
  bf16x8 af0 = *(const bf16x8*)(sA + ((2 * w) * 64 + lane) * 8);
  bf16x8 af1 = *(const bf16x8*)(sA + ((2 * w + 1) * 64 + lane) * 8);

  const f32x16 Z = {0.f,0.f,0.f,0.f,0.f,0.f,0.f,0.f,0.f,0.f,0.f,0.f,0.f,0.f,0.f,0.f};
  float m0 = 3.4e38f, m1 = 3.4e38f;
  int rowbase = rq * 2048;

  #pragma unroll 1
  for (int c = 0; c < 4; ++c) {       // 4 chunks of 512 rows
    // Pack 2 rows/thread ({t, 256+t}: keeps ds_write lane-stride 1).
    #pragma unroll
    for (int h = 0; h < 2; ++h) {
      int p = h * 256 + t;            // local row in chunk
      int gp = rowbase + c * 512 + p;
      uint4 lo, hi;
      pack_halves(&lo, &hi, Bs[gp * 3], Bs[gp * 3 + 1], Bs[gp * 3 + 2], true);
      unsigned short* u0 = sB + ((p >> 5) * 64 + (p & 31)) * 8;
      *(uint4*)u0 = lo;
      *(uint4*)(u0 + 32 * 8) = hi;
    }
    __syncthreads();
    // 16 rowtiles: 1 lane-sequential ds_read_b128 + 2 MFMA + 16 min3 each.
    #pragma unroll 4
    for (int rt = 0; rt < 16; ++rt) {
      bf16x8 bf = *(const bf16x8*)(sB + (rt * 64 + lane) * 8);
      f32x16 d0 = __builtin_amdgcn_mfma_f32_32x32x16_bf16(bf, af0, Z, 0, 0, 0);
      f32x16 d1 = __builtin_amdgcn_mfma_f32_32x32x16_bf16(bf, af1, Z, 0, 0, 0);
      #pragma unroll
      for (int r = 0; r < 16; r += 2) {
        m0 = fminf(fminf(m0, d0[r]), d0[r + 1]);   // v_min3_f32
        m1 = fminf(fminf(m1, d1[r]), d1[r + 1]);
      }
    }
    __syncthreads();                  // sB reads done before next pack
  }

  m0 = fminf(m0, __shfl_xor(m0, 32, 64));   // merge complementary row halves
  m1 = fminf(m1, __shfl_xor(m1, 32, 64));
  if (lane < 32) {
    float* dst = partial + (size_t)rq * TOTAL + (size_t)side * NPTS + cg * 256;
    dst[w * 64 + lane]      = fmaxf(m0, 0.f);
    dst[w * 64 + 32 + lane] = fmaxf(m1, 0.f);
  }
}

// Reduce: min over RSPLIT partials per slot, block-sum, one atomicAdd/block.
// out[0] was zeroed by chamfer_nn (stream-ordered before this kernel).
__global__ __launch_bounds__(TPB) void chamfer_reduce(
    const float* __restrict__ partial, float* __restrict__ out) {
  int t = threadIdx.x;
  int s = blockIdx.x * TPB + t;       // slot 0..65535
  float v = partial[s];
  #pragma unroll
  for (int r = 1; r < RSPLIT; ++r)
    v = fminf(v, partial[(size_t)r * TOTAL + s]);
  #pragma unroll
  for (int off = 32; off > 0; off >>= 1) v += __shfl_down(v, off, 64);
  __shared__ float wsum[4];
  int wave = t >> 6, lane = t & 63;
  if (lane == 0) wsum[wave] = v;
  __syncthreads();
  if (t == 0) {
    float tot = (wsum[0] + wsum[1]) + (wsum[2] + wsum[3]);
    atomicAdd(out, tot * (1.f / (float)(BATCH * NPTS)));
  }
}

extern "C" void kernel_launch(void* const* d_in, const int* in_sizes, int n_in,
                              void* d_out, int out_size, void* d_ws, size_t ws_size,
                              hipStream_t stream) {
  const float* pred = (const float*)d_in[0];
  const float* gt   = (const float*)d_in[1];
  float* out        = (float*)d_out;
  float* partial    = (float*)d_ws;   // RSPLIT x 65536 floats = 1 MB

  chamfer_nn<<<dim3(GRID), dim3(TPB), 0, stream>>>(pred, gt, partial, out);
  chamfer_reduce<<<dim3(TOTAL / TPB), dim3(TPB), 0, stream>>>(partial, out);
}